// Round 20
// baseline (24.153 us; speedup 1.0000x reference)
//
#include <hip/hip_runtime.h>

static constexpr int Tn = 4096;
static constexpr int Bn = 256;
static constexpr int Hn = 32;
static constexpr int K_CH = 128;          // chunks along T; 2 chains per wave
static constexpr int S_CH = Tn / K_CH;    // 32 owned steps per chunk
static constexpr int L_WU = 8;            // warmup steps (contraction burn-in)
static constexpr int NGRP = (S_CH + L_WU) / 4;  // 10 groups per chain
static constexpr int GW = L_WU / 4;       // 2: first group that stores y

typedef float f4 __attribute__((ext_vector_type(4)));
typedef __fp16 hp2 __attribute__((ext_vector_type(2)));   // cvt_pkrtz result type
typedef _Float16 h8 __attribute__((ext_vector_type(8)));  // MFMA operand type

__device__ __forceinline__ h8 pack_h8(float a, float b, float c, float d,
                                      float e, float f, float g, float h) {
    union { hp2 p[4]; h8 v; } u;
    u.p[0] = __builtin_amdgcn_cvt_pkrtz(a, b);
    u.p[1] = __builtin_amdgcn_cvt_pkrtz(c, d);
    u.p[2] = __builtin_amdgcn_cvt_pkrtz(e, f);
    u.p[3] = __builtin_amdgcn_cvt_pkrtz(g, h);
    return u.v;
}

// Full-rate-VALU reciprocal for x in [1, 2^54]: magic seed + 2 Newton
// iterations -> rel err ~1.2e-5 (numerics proven in r15: absmax unchanged).
// Moves 9 of 18 per-step ops OFF the (CU-shared, oversubscribed) trans pipe.
__device__ __forceinline__ float rcp_nt(float x) {
    float y = __int_as_float(0x7EF127EA - __float_as_int(x));
    y = y * __builtin_fmaf(-x, y, 2.0f);
    y = y * __builtin_fmaf(-x, y, 2.0f);
    return y;
}
// sigmoid-ish state map: r = 1/(exp2(s)+1); exp2 stays on trans pipe
__device__ __forceinline__ float sigr(float s) {
    return rcp_nt(__builtin_amdgcn_exp2f(s) + 1.0f);
}

// Per wave: 16 batches x TWO chunk-chains (r17 structure, the measured
// trans-saturation point). Model (r8/r16/r17/r18): kernel is transcendental-
// throughput-bound at CU level -- TLP dead, ILP saturates at 2 chains,
// total trans instrs x 8cy ~= entire runtime. This round halves trans count
// (rcp -> Newton on VALU). Slot-semantic MFMA layout: slot (g,e) := hidden
// index ROW(g,e) = (e<4) ? 4g+e : 16+4g+(e-4); state output feeds next B
// operand with ZERO cross-lane moves. State r = (1-h)/2 in f16. Head via
// MFMA (wd' broadcast); row-sum init via MFMA against ones.
__global__ __launch_bounds__(64) void rnn_mfma_kernel(
    const float* __restrict__ x, const float* __restrict__ h0,
    const float* __restrict__ Wih, const float* __restrict__ Whh,
    const float* __restrict__ bih, const float* __restrict__ bhh,
    const float* __restrict__ Wd, const float* __restrict__ bd,
    float* __restrict__ y_out, float* __restrict__ h_out) {
    const int lid = threadIdx.x;
    const int j = lid & 15;               // batch within tile; also A's m index
    const int g = lid >> 4;               // lane group (0..3)
    const int b = blockIdx.x * 16 + j;
    const int p = blockIdx.y;             // chain pair
    const int kcA = 2 * p, kcB = 2 * p + 1;
    const int r0 = 4 * g;

    const float cS = 2.8853900817779268f; // 2*log2(e)
    const float nc = -2.0f * cS;

    // A fragments, slot-permuted: elems = W'[row][r0..r0+3, 16+r0..16+r0+3]
    auto ldafrag = [&](int row) -> h8 {
        f4 w0 = *reinterpret_cast<const f4*>(Whh + row * Hn + r0);
        f4 w1 = *reinterpret_cast<const f4*>(Whh + row * Hn + 16 + r0);
        return pack_h8(nc * w0.x, nc * w0.y, nc * w0.z, nc * w0.w,
                       nc * w1.x, nc * w1.y, nc * w1.z, nc * w1.w);
    };
    const h8 aA = ldafrag(j);             // rows 0..15  (accA)
    const h8 aB = ldafrag(16 + j);        // rows 16..31 (accB)
    const f4 wdA = nc * (*reinterpret_cast<const f4*>(Wd + r0));
    const f4 wdB = nc * (*reinterpret_cast<const f4*>(Wd + 16 + r0));
    const h8 aY = pack_h8(wdA[0], wdA[1], wdA[2], wdA[3],
                          wdB[0], wdB[1], wdB[2], wdB[3]);

    // row-sum init via MFMA against all-ones B (permutation-invariant)
    const _Float16 one = (_Float16)1.0f;
    const h8 ones = h8{one, one, one, one, one, one, one, one};
    const f4 zero4 = {0.f, 0.f, 0.f, 0.f};
    f4 sA = __builtin_amdgcn_mfma_f32_16x16x32_f16(aA, ones, zero4, 0, 0, 0);
    f4 sB = __builtin_amdgcn_mfma_f32_16x16x32_f16(aB, ones, zero4, 0, 0, 0);
    f4 sY = __builtin_amdgcn_mfma_f32_16x16x32_f16(aY, ones, zero4, 0, 0, 0);

    const f4 bihA = *reinterpret_cast<const f4*>(bih + r0);
    const f4 bihB = *reinterpret_cast<const f4*>(bih + 16 + r0);
    const f4 bhhA = *reinterpret_cast<const f4*>(bhh + r0);
    const f4 bhhB = *reinterpret_cast<const f4*>(bhh + 16 + r0);
    f4 baseA, baseB;
#pragma unroll
    for (int r = 0; r < 4; ++r) {
        baseA[r] = __builtin_fmaf(-0.5f, sA[r], cS * (bihA[r] + bhhA[r]));
        baseB[r] = __builtin_fmaf(-0.5f, sB[r], cS * (bihB[r] + bhhB[r]));
    }
    const f4 wihA = cS * (*reinterpret_cast<const f4*>(Wih + r0));
    const f4 wihB = cS * (*reinterpret_cast<const f4*>(Wih + 16 + r0));
    const float ybase = __builtin_fmaf(-0.5f, sY[0], cS * bd[0]);
    const f4 ybase4 = {ybase, ybase, ybase, ybase};

    // exact h0 state for chunk 0 (applied at gg==GW); r = (1-h)/2
    f4 hA0 = *reinterpret_cast<const f4*>(h0 + b * Hn + r0);
    f4 hB0 = *reinterpret_cast<const f4*>(h0 + b * Hn + 16 + r0);
    const h8 hp = pack_h8(__builtin_fmaf(-0.5f, hA0.x, 0.5f),
                          __builtin_fmaf(-0.5f, hA0.y, 0.5f),
                          __builtin_fmaf(-0.5f, hA0.z, 0.5f),
                          __builtin_fmaf(-0.5f, hA0.w, 0.5f),
                          __builtin_fmaf(-0.5f, hB0.x, 0.5f),
                          __builtin_fmaf(-0.5f, hB0.y, 0.5f),
                          __builtin_fmaf(-0.5f, hB0.z, 0.5f),
                          __builtin_fmaf(-0.5f, hB0.w, 0.5f));

    const _Float16 hf = (_Float16)0.5f;
    h8 BfA = h8{hf, hf, hf, hf, hf, hf, hf, hf};
    h8 BfB = BfA;
    const bool reA = (kcA == 0);          // chain A of pair 0 = exact chunk

    const float* xpA = x + (size_t)b * Tn + 32 * kcA - L_WU;
    const float* xpB = x + (size_t)b * Tn + 32 * kcB - L_WU;
    float* ypA = y_out + (size_t)b * Tn + 32 * kcA - L_WU;
    float* ypB = y_out + (size_t)b * Tn + 32 * kcB - L_WU;

    auto ldA = [&](int t) -> f4 {
        int i = (reA && t < GW) ? GW : t;   // chunk 0: clamp into-bounds
        if (i > NGRP - 1) i = NGRP - 1;
        return *reinterpret_cast<const f4*>(xpA + i * 4);
    };
    auto ldB = [&](int t) -> f4 {
        int i = t > NGRP - 1 ? NGRP - 1 : t;
        return *reinterpret_cast<const f4*>(xpB + i * 4);
    };

    auto stepc = [&](h8& Bf, float xt, f4& rA, f4& rB) {
        f4 cA, cB;
#pragma unroll
        for (int r = 0; r < 4; ++r) {
            cA[r] = __builtin_fmaf(xt, wihA[r], baseA[r]);
            cB[r] = __builtin_fmaf(xt, wihB[r], baseB[r]);
        }
        f4 accA = __builtin_amdgcn_mfma_f32_16x16x32_f16(aA, Bf, cA, 0, 0, 0);
        f4 accB = __builtin_amdgcn_mfma_f32_16x16x32_f16(aB, Bf, cB, 0, 0, 0);
#pragma unroll
        for (int r = 0; r < 4; ++r) {
            rA[r] = sigr(accA[r]);
            rB[r] = sigr(accB[r]);
        }
        Bf = pack_h8(rA[0], rA[1], rA[2], rA[3], rB[0], rB[1], rB[2], rB[3]);
    };
    auto heady = [&](const h8& Bf) -> f4 {
        return __builtin_amdgcn_mfma_f32_16x16x32_f16(aY, Bf, ybase4, 0, 0, 0);
    };
    auto yfin = [&](float t) -> float {
        return __builtin_fmaf(-2.0f, sigr(t), 1.0f);
    };

    f4 qA0 = ldA(0), qA1 = ldA(1);
    f4 qB0 = ldB(0), qB1 = ldB(1);
    f4 rAA, rBA, rAB, rBB;                // chain B's f32 state persists

    for (int gg = 0; gg < NGRP; ++gg) {
        if (reA && gg == GW) BfA = hp;    // wave-uniform exact re-init
        f4 cA = qA0; qA0 = qA1; qA1 = ldA(gg + 2);
        f4 cB = qB0; qB0 = qB1; qB1 = ldB(gg + 2);
        stepc(BfA, cA.x, rAA, rBA);  stepc(BfB, cB.x, rAB, rBB);
        f4 fA0 = heady(BfA);         f4 fB0 = heady(BfB);
        stepc(BfA, cA.y, rAA, rBA);  stepc(BfB, cB.y, rAB, rBB);
        f4 fA1 = heady(BfA);         f4 fB1 = heady(BfB);
        stepc(BfA, cA.z, rAA, rBA);  stepc(BfB, cB.z, rAB, rBB);
        f4 fA2 = heady(BfA);         f4 fB2 = heady(BfB);
        stepc(BfA, cA.w, rAA, rBA);  stepc(BfB, cB.w, rAB, rBB);
        f4 fA3 = heady(BfA);         f4 fB3 = heady(BfB);
        if (gg >= GW && g == 0) {
            f4 va = {yfin(fA0[0]), yfin(fA1[0]), yfin(fA2[0]), yfin(fA3[0])};
            f4 vb = {yfin(fB0[0]), yfin(fB1[0]), yfin(fB2[0]), yfin(fB3[0])};
            *reinterpret_cast<f4*>(ypA + gg * 4) = va;
            *reinterpret_cast<f4*>(ypB + gg * 4) = vb;
        }
    }

    if (kcB == K_CH - 1) {   // final h from chain B's hot f32 r-values
        f4 hA = {__builtin_fmaf(-2.0f, rAB[0], 1.0f),
                 __builtin_fmaf(-2.0f, rAB[1], 1.0f),
                 __builtin_fmaf(-2.0f, rAB[2], 1.0f),
                 __builtin_fmaf(-2.0f, rAB[3], 1.0f)};
        f4 hB = {__builtin_fmaf(-2.0f, rBB[0], 1.0f),
                 __builtin_fmaf(-2.0f, rBB[1], 1.0f),
                 __builtin_fmaf(-2.0f, rBB[2], 1.0f),
                 __builtin_fmaf(-2.0f, rBB[3], 1.0f)};
        *reinterpret_cast<f4*>(h_out + b * Hn + r0) = hA;
        *reinterpret_cast<f4*>(h_out + b * Hn + 16 + r0) = hB;
    }
}

extern "C" void kernel_launch(void* const* d_in, const int* in_sizes, int n_in,
                              void* d_out, int out_size, void* d_ws, size_t ws_size,
                              hipStream_t stream) {
    (void)in_sizes; (void)n_in; (void)out_size; (void)d_ws; (void)ws_size;
    const float* x   = (const float*)d_in[0];
    const float* ph  = (const float*)d_in[1];
    const float* Wih = (const float*)d_in[2];
    const float* Whh = (const float*)d_in[3];
    const float* bih = (const float*)d_in[4];
    const float* bhh = (const float*)d_in[5];
    const float* Wd  = (const float*)d_in[6];
    const float* bd  = (const float*)d_in[7];
    float* yout = (float*)d_out;
    float* hout = yout + (size_t)Bn * Tn;
    rnn_mfma_kernel<<<dim3(Bn / 16, K_CH / 2), dim3(64), 0, stream>>>(
        x, ph, Wih, Whh, bih, bhh, Wd, bd, yout, hout);
}

// Round 21
// 20.721 us; speedup vs baseline: 1.1656x; 1.1656x over previous
//
#include <hip/hip_runtime.h>

static constexpr int Tn = 4096;
static constexpr int Bn = 256;
static constexpr int Hn = 32;
static constexpr int K_CH = 128;          // chunks along T; 2 chains per wave
static constexpr int S_CH = Tn / K_CH;    // 32 owned steps per chunk
static constexpr int L_WU = 8;            // warmup steps (contraction burn-in)
static constexpr int NGRP = (S_CH + L_WU) / 4;  // 10 groups per chain
static constexpr int GW = L_WU / 4;       // 2: first group that stores y

typedef float f4 __attribute__((ext_vector_type(4)));
typedef __fp16 hp2 __attribute__((ext_vector_type(2)));   // cvt_pkrtz result type
typedef _Float16 h8 __attribute__((ext_vector_type(8)));  // MFMA operand type

__device__ __forceinline__ h8 pack_h8(float a, float b, float c, float d,
                                      float e, float f, float g, float h) {
    union { hp2 p[4]; h8 v; } u;
    u.p[0] = __builtin_amdgcn_cvt_pkrtz(a, b);
    u.p[1] = __builtin_amdgcn_cvt_pkrtz(c, d);
    u.p[2] = __builtin_amdgcn_cvt_pkrtz(e, f);
    u.p[3] = __builtin_amdgcn_cvt_pkrtz(g, h);
    return u.v;
}

// Per wave: 16 batches x TWO chunk-chains, software-interleaved (r17: the
// measured issue-saturation point -- chain B's instructions fill chain A's
// MFMA/exp/rcp latency). TLP dead (r8/r16); >2 chains net-negative via
// warmup overhead (r18); trans-replacement negative (r15/r20).
// Slot-semantic MFMA layout: slot (g,e) := hidden index
//   ROW(g,e) = (e<4) ? 4g+e : 16+4g+(e-4)
// B slot (g,e) = r_{ROW(g,e)} == exactly this lane's 8 sigmoid outputs, and
// A slot (g,e) = W'[m][ROW(g,e)]. Output feeds next B operand with ZERO
// cross-lane moves. State: r = 1/(exp2(s')+1) = (1-h)/2 in f16.
// Head via MFMA (wd' broadcast); row-sum init via MFMA against ones.
__global__ __launch_bounds__(64) void rnn_mfma_kernel(
    const float* __restrict__ x, const float* __restrict__ h0,
    const float* __restrict__ Wih, const float* __restrict__ Whh,
    const float* __restrict__ bih, const float* __restrict__ bhh,
    const float* __restrict__ Wd, const float* __restrict__ bd,
    float* __restrict__ y_out, float* __restrict__ h_out) {
    const int lid = threadIdx.x;
    const int j = lid & 15;               // batch within tile; also A's m index
    const int g = lid >> 4;               // lane group (0..3)
    const int b = blockIdx.x * 16 + j;
    const int p = blockIdx.y;             // chain pair
    const int kcA = 2 * p, kcB = 2 * p + 1;
    const int r0 = 4 * g;

    const float cS = 2.8853900817779268f; // 2*log2(e)
    const float nc = -2.0f * cS;

    // A fragments, slot-permuted: elems = W'[row][r0..r0+3, 16+r0..16+r0+3]
    auto ldafrag = [&](int row) -> h8 {
        f4 w0 = *reinterpret_cast<const f4*>(Whh + row * Hn + r0);
        f4 w1 = *reinterpret_cast<const f4*>(Whh + row * Hn + 16 + r0);
        return pack_h8(nc * w0.x, nc * w0.y, nc * w0.z, nc * w0.w,
                       nc * w1.x, nc * w1.y, nc * w1.z, nc * w1.w);
    };
    const h8 aA = ldafrag(j);             // rows 0..15  (accA)
    const h8 aB = ldafrag(16 + j);        // rows 16..31 (accB)
    const f4 wdA = nc * (*reinterpret_cast<const f4*>(Wd + r0));
    const f4 wdB = nc * (*reinterpret_cast<const f4*>(Wd + 16 + r0));
    const h8 aY = pack_h8(wdA[0], wdA[1], wdA[2], wdA[3],
                          wdB[0], wdB[1], wdB[2], wdB[3]);

    // row-sum init via MFMA against all-ones B (permutation-invariant)
    const _Float16 one = (_Float16)1.0f;
    const h8 ones = h8{one, one, one, one, one, one, one, one};
    const f4 zero4 = {0.f, 0.f, 0.f, 0.f};
    f4 sA = __builtin_amdgcn_mfma_f32_16x16x32_f16(aA, ones, zero4, 0, 0, 0);
    f4 sB = __builtin_amdgcn_mfma_f32_16x16x32_f16(aB, ones, zero4, 0, 0, 0);
    f4 sY = __builtin_amdgcn_mfma_f32_16x16x32_f16(aY, ones, zero4, 0, 0, 0);

    const f4 bihA = *reinterpret_cast<const f4*>(bih + r0);
    const f4 bihB = *reinterpret_cast<const f4*>(bih + 16 + r0);
    const f4 bhhA = *reinterpret_cast<const f4*>(bhh + r0);
    const f4 bhhB = *reinterpret_cast<const f4*>(bhh + 16 + r0);
    f4 baseA, baseB;
#pragma unroll
    for (int r = 0; r < 4; ++r) {
        baseA[r] = __builtin_fmaf(-0.5f, sA[r], cS * (bihA[r] + bhhA[r]));
        baseB[r] = __builtin_fmaf(-0.5f, sB[r], cS * (bihB[r] + bhhB[r]));
    }
    const f4 wihA = cS * (*reinterpret_cast<const f4*>(Wih + r0));
    const f4 wihB = cS * (*reinterpret_cast<const f4*>(Wih + 16 + r0));
    const float ybase = __builtin_fmaf(-0.5f, sY[0], cS * bd[0]);
    const f4 ybase4 = {ybase, ybase, ybase, ybase};

    // exact h0 state for chunk 0 (applied at gg==GW); r = (1-h)/2
    f4 hA0 = *reinterpret_cast<const f4*>(h0 + b * Hn + r0);
    f4 hB0 = *reinterpret_cast<const f4*>(h0 + b * Hn + 16 + r0);
    const h8 hp = pack_h8(__builtin_fmaf(-0.5f, hA0.x, 0.5f),
                          __builtin_fmaf(-0.5f, hA0.y, 0.5f),
                          __builtin_fmaf(-0.5f, hA0.z, 0.5f),
                          __builtin_fmaf(-0.5f, hA0.w, 0.5f),
                          __builtin_fmaf(-0.5f, hB0.x, 0.5f),
                          __builtin_fmaf(-0.5f, hB0.y, 0.5f),
                          __builtin_fmaf(-0.5f, hB0.z, 0.5f),
                          __builtin_fmaf(-0.5f, hB0.w, 0.5f));

    const _Float16 hf = (_Float16)0.5f;
    h8 BfA = h8{hf, hf, hf, hf, hf, hf, hf, hf};
    h8 BfB = BfA;
    const bool reA = (kcA == 0);          // chain A of pair 0 = exact chunk

    const float* xpA = x + (size_t)b * Tn + 32 * kcA - L_WU;
    const float* xpB = x + (size_t)b * Tn + 32 * kcB - L_WU;
    float* ypA = y_out + (size_t)b * Tn + 32 * kcA - L_WU;
    float* ypB = y_out + (size_t)b * Tn + 32 * kcB - L_WU;

    auto ldA = [&](int t) -> f4 {
        int i = (reA && t < GW) ? GW : t;   // chunk 0: clamp into-bounds
        if (i > NGRP - 1) i = NGRP - 1;
        return *reinterpret_cast<const f4*>(xpA + i * 4);
    };
    auto ldB = [&](int t) -> f4 {
        int i = t > NGRP - 1 ? NGRP - 1 : t;
        return *reinterpret_cast<const f4*>(xpB + i * 4);
    };

    auto stepc = [&](h8& Bf, float xt, f4& rA, f4& rB) {
        f4 cA, cB;
#pragma unroll
        for (int r = 0; r < 4; ++r) {
            cA[r] = __builtin_fmaf(xt, wihA[r], baseA[r]);
            cB[r] = __builtin_fmaf(xt, wihB[r], baseB[r]);
        }
        f4 accA = __builtin_amdgcn_mfma_f32_16x16x32_f16(aA, Bf, cA, 0, 0, 0);
        f4 accB = __builtin_amdgcn_mfma_f32_16x16x32_f16(aB, Bf, cB, 0, 0, 0);
#pragma unroll
        for (int r = 0; r < 4; ++r) {
            rA[r] = __builtin_amdgcn_rcpf(__builtin_amdgcn_exp2f(accA[r]) + 1.0f);
            rB[r] = __builtin_amdgcn_rcpf(__builtin_amdgcn_exp2f(accB[r]) + 1.0f);
        }
        Bf = pack_h8(rA[0], rA[1], rA[2], rA[3], rB[0], rB[1], rB[2], rB[3]);
    };
    auto heady = [&](const h8& Bf) -> f4 {
        return __builtin_amdgcn_mfma_f32_16x16x32_f16(aY, Bf, ybase4, 0, 0, 0);
    };
    auto yfin = [&](float t) -> float {
        float e = __builtin_amdgcn_exp2f(t);
        return __builtin_fmaf(-2.0f, __builtin_amdgcn_rcpf(e + 1.0f), 1.0f);
    };

    f4 qA0 = ldA(0), qA1 = ldA(1);
    f4 qB0 = ldB(0), qB1 = ldB(1);
    f4 rAA, rBA, rAB, rBB;                // chain B's f32 state persists

    for (int gg = 0; gg < NGRP; ++gg) {
        if (reA && gg == GW) BfA = hp;    // wave-uniform exact re-init
        f4 cA = qA0; qA0 = qA1; qA1 = ldA(gg + 2);
        f4 cB = qB0; qB0 = qB1; qB1 = ldB(gg + 2);
        stepc(BfA, cA.x, rAA, rBA);  stepc(BfB, cB.x, rAB, rBB);
        f4 fA0 = heady(BfA);         f4 fB0 = heady(BfB);
        stepc(BfA, cA.y, rAA, rBA);  stepc(BfB, cB.y, rAB, rBB);
        f4 fA1 = heady(BfA);         f4 fB1 = heady(BfB);
        stepc(BfA, cA.z, rAA, rBA);  stepc(BfB, cB.z, rAB, rBB);
        f4 fA2 = heady(BfA);         f4 fB2 = heady(BfB);
        stepc(BfA, cA.w, rAA, rBA);  stepc(BfB, cB.w, rAB, rBB);
        f4 fA3 = heady(BfA);         f4 fB3 = heady(BfB);
        if (gg >= GW && g == 0) {
            f4 va = {yfin(fA0[0]), yfin(fA1[0]), yfin(fA2[0]), yfin(fA3[0])};
            f4 vb = {yfin(fB0[0]), yfin(fB1[0]), yfin(fB2[0]), yfin(fB3[0])};
            *reinterpret_cast<f4*>(ypA + gg * 4) = va;
            *reinterpret_cast<f4*>(ypB + gg * 4) = vb;
        }
    }

    if (kcB == K_CH - 1) {   // final h from chain B's hot f32 r-values
        f4 hA = {__builtin_fmaf(-2.0f, rAB[0], 1.0f),
                 __builtin_fmaf(-2.0f, rAB[1], 1.0f),
                 __builtin_fmaf(-2.0f, rAB[2], 1.0f),
                 __builtin_fmaf(-2.0f, rAB[3], 1.0f)};
        f4 hB = {__builtin_fmaf(-2.0f, rBB[0], 1.0f),
                 __builtin_fmaf(-2.0f, rBB[1], 1.0f),
                 __builtin_fmaf(-2.0f, rBB[2], 1.0f),
                 __builtin_fmaf(-2.0f, rBB[3], 1.0f)};
        *reinterpret_cast<f4*>(h_out + b * Hn + r0) = hA;
        *reinterpret_cast<f4*>(h_out + b * Hn + 16 + r0) = hB;
    }
}

extern "C" void kernel_launch(void* const* d_in, const int* in_sizes, int n_in,
                              void* d_out, int out_size, void* d_ws, size_t ws_size,
                              hipStream_t stream) {
    (void)in_sizes; (void)n_in; (void)out_size; (void)d_ws; (void)ws_size;
    const float* x   = (const float*)d_in[0];
    const float* ph  = (const float*)d_in[1];
    const float* Wih = (const float*)d_in[2];
    const float* Whh = (const float*)d_in[3];
    const float* bih = (const float*)d_in[4];
    const float* bhh = (const float*)d_in[5];
    const float* Wd  = (const float*)d_in[6];
    const float* bd  = (const float*)d_in[7];
    float* yout = (float*)d_out;
    float* hout = yout + (size_t)Bn * Tn;
    rnn_mfma_kernel<<<dim3(Bn / 16, K_CH / 2), dim3(64), 0, stream>>>(
        x, ph, Wih, Whh, bih, bhh, Wd, bd, yout, hout);
}